// Round 13
// baseline (515.225 us; speedup 1.0000x reference)
//
#include <hip/hip_runtime.h>

// EdgeGATConv on MI355X — R8 (3rd resubmit; GPU-acquisition timeouts):
// two-phase binned fill (kills scatter write-amp).
// R9 counters: single-pass cursor-scatter wrote 64B/record (100.6MB for 25.6MB
// payload) + RMW fetches; lines never combine (uniform dst spread x 8 XCDs).
// Fix: bin by dst>>9 (196 bins). Invariant: bin_start[b] == row_start[b<<9],
// so pass1 writes bin-grouped records into rec's OWN interval (no extra ws):
//   k_fill_p1: per 4096-edge chunk: compute w (coalesced ea), LDS hist+scan+
//              scatter by bin, flush coalesced runs to atomically-reserved
//              per-bin sub-ranges. Writes ~= payload.
//   k_fill_p2: one block per bin: buffer entire bin interval in LDS (<=9216
//              recs, 147KB), then per-dst cursor scatter within the 131KB
//              window -> single-XCD L2 residency -> writes combine.
// Per-edge arithmetic identical to R7 (no numerics change).

#define N_NODES 100000
#define N_EDGES 1600000
#define SCAN_B 1024
#define SCAN_NBLK ((N_NODES + SCAN_B - 1) / SCAN_B)   // 98
#define BINSH 9
#define NBIN 196                                       // ceil(100000/512)
#define CHUNK 4096
#define NBLK_P1 ((N_EDGES + CHUNK - 1) / CHUNK)        // 391
#define CAP 9216                                       // max bin recs in LDS (mean 8163, sigma~90)

typedef float f32x4 __attribute__((ext_vector_type(4)));

// float -> bf16 bits, round-to-nearest-even (no NaN inputs here)
static __device__ __forceinline__ unsigned int f2bf(float f) {
    unsigned int u = __float_as_uint(f);
    return (u + 0x7fffu + ((u >> 16) & 1u)) >> 16;
}
static __device__ __forceinline__ float bf2f(unsigned int bits16) {
    return __uint_as_float(bits16 << 16);
}

// V buffer layout (floats): [0..63] V_edge[k*4+h], [64..67] b_edge dot,
// [68..579] uD[k*4+h] (k<128), [580..583] bD[h]
__global__ __launch_bounds__(640) void k_prep(
    const float* __restrict__ We, const float* __restrict__ be,
    const float* __restrict__ att_e, const float* __restrict__ Wdst,
    const float* __restrict__ bdst, const float* __restrict__ att_d,
    float* __restrict__ V)
{
    const int t = threadIdx.x;
    if (t < 64) {
        const int k = t >> 2, h = t & 3;
        float acc = 0.f;
        for (int c = 0; c < 16; ++c)
            acc += We[k * 64 + h * 16 + c] * att_e[h * 16 + c];
        V[k * 4 + h] = acc;
        if (t < 4) {
            float b = 0.f;
            for (int c = 0; c < 16; ++c)
                b += be[t * 16 + c] * att_e[t * 16 + c];
            V[64 + t] = b;
        }
    } else if (t < 576) {
        const int j = t - 64;            // 0..511
        const int k = j >> 2, h = j & 3;
        float acc = 0.f;
        for (int c = 0; c < 16; ++c)
            acc += Wdst[k * 64 + h * 16 + c] * att_d[h * 16 + c];
        V[68 + j] = acc;
    } else if (t < 580) {
        const int h = t - 576;
        float b = 0.f;
        for (int c = 0; c < 16; ++c)
            b += bdst[h * 16 + c] * att_d[h * 16 + c];
        V[580 + h] = b;
    }
}

__global__ __launch_bounds__(256) void k_node_proj(
    const float* __restrict__ x, const float* __restrict__ Wsrc,
    const float* __restrict__ bsrc, const float* __restrict__ att_src,
    const float* __restrict__ Vbuf, unsigned short* __restrict__ spbf,
    float* __restrict__ alpha_sn, float* __restrict__ alpha_dn)
{
    __shared__ float xs[32 * 132];      // 16.9 KB, stride 132 breaks bank aliasing
    __shared__ float uDs[4 * 132];      // transposed+padded: uDs[h*132 + k]
    __shared__ float bDs[4];
    const int tid = threadIdx.x;
    const int nbase = blockIdx.x * 32;

    // stage x tile: 32 rows x 128 floats = 1024 float4 (coalesced)
    {
        const f32x4* xsrc = (const f32x4*)(x + (size_t)nbase * 128);
#pragma unroll
        for (int i = 0; i < 4; ++i) {
            const int idx = tid + i * 256;      // 0..1023
            const int n = idx >> 5, q = idx & 31;
            *(f32x4*)&xs[n * 132 + q * 4] = xsrc[idx];
        }
#pragma unroll
        for (int i = 0; i < 2; ++i) {
            const int j = tid + i * 256;        // 0..511 : uD[k*4+h]
            const int k = j >> 2, h = j & 3;
            uDs[h * 132 + k] = Vbuf[68 + j];
        }
        if (tid < 4) bDs[tid] = Vbuf[580 + tid];
    }
    __syncthreads();

    const int col = tid & 63;
    const int g = tid >> 6;                     // wave id 0..3, nodes g*8..g*8+7

    float accS[8];
#pragma unroll
    for (int i = 0; i < 8; ++i) accS[i] = 0.f;

    for (int k4 = 0; k4 < 128; k4 += 4) {
        f32x4 xv[8];
#pragma unroll
        for (int i = 0; i < 8; ++i)
            xv[i] = *(const f32x4*)&xs[(g * 8 + i) * 132 + k4];  // broadcast: free
#pragma unroll
        for (int kk = 0; kk < 4; ++kk) {
            const float wsv = Wsrc[(k4 + kk) * 64 + col];        // L1-resident
#pragma unroll
            for (int i = 0; i < 8; ++i)
                accS[i] = fmaf(xv[i][kk], wsv, accS[i]);
        }
    }

    // alpha_dn GEMV: lane owns (node li, head lh), half the k-range; pair-reduce.
    const int li = col & 7, lh = (col >> 3) & 3, khalf = (col >> 5) * 64;
    float ad = 0.f;
#pragma unroll
    for (int kq = 0; kq < 16; ++kq) {
        const f32x4 xq = *(const f32x4*)&xs[(g * 8 + li) * 132 + khalf + kq * 4];
        const f32x4 uq = *(const f32x4*)&uDs[lh * 132 + khalf + kq * 4];
#pragma unroll
        for (int j = 0; j < 4; ++j)
            ad = fmaf(xq[j], uq[j], ad);
    }
    ad += __shfl_xor(ad, 32);

    const float bs = bsrc[col];
    const float as_ = att_src[col];
    const int h = col >> 4;
#pragma unroll
    for (int i = 0; i < 8; ++i) {
        const int n = nbase + g * 8 + i;
        const float vS = accS[i] + bs;
        spbf[(size_t)n * 64 + col] = (unsigned short)f2bf(vS);
        float t1 = vS * as_;
#pragma unroll
        for (int off = 8; off >= 1; off >>= 1)
            t1 += __shfl_xor(t1, off, 16);
        if ((col & 15) == 0)
            alpha_sn[n * 4 + h] = t1;
    }
    if (col < 32)
        alpha_dn[(nbase + g * 8 + li) * 4 + lh] = ad + bDs[lh];
}

__global__ __launch_bounds__(256) void k_hist(const int* __restrict__ ei,
                                               int* __restrict__ cnt)
{
    const int e = blockIdx.x * 256 + threadIdx.x;
    if (e >= N_EDGES) return;
    atomicAdd(&cnt[ei[N_EDGES + e]], 1);
}

__global__ __launch_bounds__(256) void k_scan_part(const int* __restrict__ cnt,
                                                    int* __restrict__ partial)
{
    __shared__ int red[4];
    const int t = threadIdx.x;
    const int base = blockIdx.x * SCAN_B + t * 4;
    int s = 0;
#pragma unroll
    for (int i = 0; i < 4; ++i) {
        const int idx = base + i;
        if (idx < N_NODES) s += cnt[idx];
    }
#pragma unroll
    for (int off = 32; off >= 1; off >>= 1)
        s += __shfl_xor(s, off, 64);
    if ((t & 63) == 0) red[t >> 6] = s;
    __syncthreads();
    if (t == 0)
        partial[blockIdx.x] = red[0] + red[1] + red[2] + red[3];
}

__global__ __launch_bounds__(128) void k_scan_top(int* __restrict__ partial)
{
    __shared__ int sums[128];
    const int t = threadIdx.x;
    sums[t] = (t < SCAN_NBLK) ? partial[t] : 0;
    __syncthreads();
#pragma unroll
    for (int off = 1; off < 128; off <<= 1) {
        int v = (t >= off) ? sums[t - off] : 0;
        __syncthreads();
        sums[t] += v;
        __syncthreads();
    }
    if (t < SCAN_NBLK) partial[t] = (t == 0) ? 0 : sums[t - 1];
}

__global__ __launch_bounds__(256) void k_scan_down(
    const int* __restrict__ cnt, const int* __restrict__ partial,
    int* __restrict__ row_start, int* __restrict__ cursor,
    int* __restrict__ bin_cursor)
{
    __shared__ int tsum[256];
    const int t = threadIdx.x;
    const int base = blockIdx.x * SCAN_B + t * 4;
    int c[4];
#pragma unroll
    for (int i = 0; i < 4; ++i) {
        const int idx = base + i;
        c[i] = (idx < N_NODES) ? cnt[idx] : 0;
    }
    const int tot = c[0] + c[1] + c[2] + c[3];
    tsum[t] = tot;
    __syncthreads();
#pragma unroll
    for (int off = 1; off < 256; off <<= 1) {
        int v = (t >= off) ? tsum[t - off] : 0;
        __syncthreads();
        tsum[t] += v;
        __syncthreads();
    }
    int run = partial[blockIdx.x] + ((t == 0) ? 0 : tsum[t - 1]);
#pragma unroll
    for (int i = 0; i < 4; ++i) {
        const int idx = base + i;
        if (idx < N_NODES) {
            row_start[idx] = run;
            cursor[idx] = run;
            if ((idx & ((1 << BINSH) - 1)) == 0)
                bin_cursor[idx >> BINSH] = run;   // bin_start[b] == row_start[b<<9]
        }
        run += c[i];
    }
    if (blockIdx.x == 0 && t == 0)
        row_start[N_NODES] = N_EDGES;
}

// Pass 1: per 4096-edge chunk, compute records {src,w01,w23,dst}, group by
// dst-bin in LDS, flush coalesced runs into atomically-reserved per-bin ranges
// of rec (bin intervals == rec intervals by the row_start invariant).
__global__ __launch_bounds__(256) void k_fill_p1(
    const int* __restrict__ ei, const float* __restrict__ ea,
    const float* __restrict__ V, const float* __restrict__ alpha_sn,
    const float* __restrict__ alpha_dn, int* __restrict__ bin_cursor,
    int4* __restrict__ rec)
{
    __shared__ float Vs[68];
    __shared__ int   hist[NBIN];            // counts -> reused as local starts
    __shared__ int   lcur[NBIN];            // LDS scatter cursors
    __shared__ int   gbase[NBIN];           // global flush bases
    __shared__ int   stmp[256];
    __shared__ int4  recs[CHUNK];           // 64 KB
    __shared__ unsigned short binOf[CHUNK]; // 8 KB

    const int tid = threadIdx.x;
    if (tid < 68) Vs[tid] = V[tid];
    for (int i = tid; i < NBIN; i += 256) hist[i] = 0;
    __syncthreads();

    const int ebase = blockIdx.x * CHUNK;
    const int n = min(CHUNK, N_EDGES - ebase);

    // phase A: histogram dst bins (coalesced ei reads)
    for (int i = 0; i < 16; ++i) {
        const int li = i * 256 + tid;
        if (li < n)
            atomicAdd(&hist[ei[N_EDGES + ebase + li] >> BINSH], 1);
    }
    __syncthreads();

    // phase B: exclusive scan; reserve global ranges
    stmp[tid] = (tid < NBIN) ? hist[tid] : 0;
    __syncthreads();
    for (int off = 1; off < 256; off <<= 1) {
        const int v = (tid >= off) ? stmp[tid - off] : 0;
        __syncthreads();
        stmp[tid] += v;
        __syncthreads();
    }
    if (tid < NBIN) {
        const int cntb = hist[tid];
        const int excl = stmp[tid] - cntb;
        lcur[tid] = excl;
        gbase[tid] = cntb ? atomicAdd(&bin_cursor[tid], cntb) : 0;
        hist[tid] = excl;                   // reuse as local start
    }
    __syncthreads();

    // phase C: compute w per edge (identical math to R7), LDS scatter by bin
#pragma unroll 2
    for (int i = 0; i < 16; ++i) {
        const int li = i * 256 + tid;
        if (li >= n) continue;
        const int e = ebase + li;
        const int src = ei[e];
        const int dst = ei[N_EDGES + e];    // block window: L1/L2-hot re-read

        const f32x4* ea4 = (const f32x4*)(ea + (size_t)e * 16);
        float ek[16];
        {
            f32x4 c0 = __builtin_nontemporal_load(ea4 + 0);
            f32x4 c1 = __builtin_nontemporal_load(ea4 + 1);
            f32x4 c2 = __builtin_nontemporal_load(ea4 + 2);
            f32x4 c3 = __builtin_nontemporal_load(ea4 + 3);
            ek[0]=c0.x; ek[1]=c0.y; ek[2]=c0.z; ek[3]=c0.w;
            ek[4]=c1.x; ek[5]=c1.y; ek[6]=c1.z; ek[7]=c1.w;
            ek[8]=c2.x; ek[9]=c2.y; ek[10]=c2.z; ek[11]=c2.w;
            ek[12]=c3.x; ek[13]=c3.y; ek[14]=c3.z; ek[15]=c3.w;
        }
        float a[4] = {Vs[64], Vs[65], Vs[66], Vs[67]};
#pragma unroll
        for (int k = 0; k < 16; ++k) {
#pragma unroll
            for (int h = 0; h < 4; ++h)
                a[h] = fmaf(ek[k], Vs[k * 4 + h], a[h]);
        }
        const float4 asn = *(const float4*)(alpha_sn + (size_t)src * 4);
        const float4 adn = *(const float4*)(alpha_dn + (size_t)dst * 4);
        float a0 = a[0] + asn.x + adn.x;
        float a1 = a[1] + asn.y + adn.y;
        float a2 = a[2] + asn.z + adn.z;
        float a3 = a[3] + asn.w + adn.w;
        a0 = (a0 >= 0.f) ? a0 : 0.2f * a0;
        a1 = (a1 >= 0.f) ? a1 : 0.2f * a1;
        a2 = (a2 >= 0.f) ? a2 : 0.2f * a2;
        a3 = (a3 >= 0.f) ? a3 : 0.2f * a3;
        const unsigned int w01 = f2bf(__expf(a0)) | (f2bf(__expf(a1)) << 16);
        const unsigned int w23 = f2bf(__expf(a2)) | (f2bf(__expf(a3)) << 16);

        const int b = dst >> BINSH;
        const int pos = atomicAdd(&lcur[b], 1);
        recs[pos] = make_int4(src, (int)w01, (int)w23, dst);
        binOf[pos] = (unsigned short)b;
    }
    __syncthreads();

    // phase D: coalesced flush of bin runs
    for (int j = tid; j < n; j += 256) {
        const int b = binOf[j];
        rec[gbase[b] + (j - hist[b])] = recs[j];
    }
}

// Pass 2: one block per bin. Buffer the whole bin interval (reads complete
// before any write), then per-dst cursor scatter confined to the 131KB
// window -> single-XCD L2 residency -> write combining.
__global__ __launch_bounds__(256) void k_fill_p2(
    const int* __restrict__ row_start, int* __restrict__ cursor,
    int4* __restrict__ rec)
{
    __shared__ int4 sbin[CAP];              // 147 KB
    const int tid = threadIdx.x;
    const int b = blockIdx.x;
    const int bs = row_start[b << BINSH];
    const int nd = (b + 1) << BINSH;
    const int be = (nd >= N_NODES) ? N_EDGES : row_start[nd];
    const int cntb = be - bs;
    const int nl = min(cntb, CAP);

    for (int j = tid; j < nl; j += 256)
        sbin[j] = rec[bs + j];
    int4 ovf[4];                            // stats: cntb<=~8600 << CAP; safety
#pragma unroll
    for (int k = 0; k < 4; ++k) {
        const int j = nl + k * 256 + tid;
        if (j < cntb) ovf[k] = rec[bs + j];
    }
    __syncthreads();

    int j = tid;
    for (; j + 768 < nl; j += 1024) {
        const int4 r0 = sbin[j], r1 = sbin[j + 256];
        const int4 r2 = sbin[j + 512], r3 = sbin[j + 768];
        const int s0 = atomicAdd(&cursor[r0.w], 1);
        const int s1 = atomicAdd(&cursor[r1.w], 1);
        const int s2 = atomicAdd(&cursor[r2.w], 1);
        const int s3 = atomicAdd(&cursor[r3.w], 1);
        rec[s0] = make_int4(r0.x, r0.y, r0.z, 0);
        rec[s1] = make_int4(r1.x, r1.y, r1.z, 0);
        rec[s2] = make_int4(r2.x, r2.y, r2.z, 0);
        rec[s3] = make_int4(r3.x, r3.y, r3.z, 0);
    }
    for (; j < nl; j += 256) {
        const int4 r0 = sbin[j];
        const int s0 = atomicAdd(&cursor[r0.w], 1);
        rec[s0] = make_int4(r0.x, r0.y, r0.z, 0);
    }
#pragma unroll
    for (int k = 0; k < 4; ++k) {
        const int jo = nl + k * 256 + tid;
        if (jo < cntb) {
            const int s0 = atomicAdd(&cursor[ovf[k].w], 1);
            rec[s0] = make_int4(ovf[k].x, ovf[k].y, ovf[k].z, 0);
        }
    }
}

// one wave per node; unroll-4 over incoming edges for memory-level parallelism
__global__ __launch_bounds__(256) void k_gather(
    const int* __restrict__ row_start, const int4* __restrict__ rec,
    const unsigned short* __restrict__ spbf, float* __restrict__ out)
{
    typedef int i32x4v __attribute__((ext_vector_type(4)));
    const int lane = threadIdx.x & 63;
    const int node = (blockIdx.x * 256 + threadIdx.x) >> 6;
    const int h = lane >> 4;
    const int base = row_start[node];
    const int end = row_start[node + 1];
    const i32x4v* rec4 = (const i32x4v*)rec;

    float acc = 0.f, denom = 0.f;
    int j = base;
    for (; j + 4 <= end; j += 4) {
        const i32x4v r0 = __builtin_nontemporal_load(rec4 + j);
        const i32x4v r1 = __builtin_nontemporal_load(rec4 + j + 1);
        const i32x4v r2 = __builtin_nontemporal_load(rec4 + j + 2);
        const i32x4v r3 = __builtin_nontemporal_load(rec4 + j + 3);
        const float v0 = bf2f(spbf[((size_t)r0.x << 6) + lane]);
        const float v1 = bf2f(spbf[((size_t)r1.x << 6) + lane]);
        const float v2 = bf2f(spbf[((size_t)r2.x << 6) + lane]);
        const float v3 = bf2f(spbf[((size_t)r3.x << 6) + lane]);
#define WEXT(r) bf2f(((h & 1) ? ((unsigned int)((h < 2) ? r.y : r.z) >> 16) \
                              : ((unsigned int)((h < 2) ? r.y : r.z) & 0xffffu)))
        const float w0 = WEXT(r0), w1 = WEXT(r1), w2 = WEXT(r2), w3 = WEXT(r3);
        denom += (w0 + w1) + (w2 + w3);
        acc = fmaf(w0, v0, acc);
        acc = fmaf(w1, v1, acc);
        acc = fmaf(w2, v2, acc);
        acc = fmaf(w3, v3, acc);
    }
    for (; j < end; ++j) {
        const i32x4v r0 = __builtin_nontemporal_load(rec4 + j);
        const float v0 = bf2f(spbf[((size_t)r0.x << 6) + lane]);
        const float w0 = WEXT(r0);
        denom += w0;
        acc = fmaf(w0, v0, acc);
    }
#undef WEXT
    __builtin_nontemporal_store(acc / (denom + 1e-16f), &out[(size_t)node * 64 + lane]);
}

extern "C" void kernel_launch(void* const* d_in, const int* in_sizes, int n_in,
                              void* d_out, int out_size, void* d_ws, size_t ws_size,
                              hipStream_t stream) {
    const float* x     = (const float*)d_in[0];
    const int*   ei    = (const int*)d_in[1];
    const float* ea    = (const float*)d_in[2];
    const float* Wsrc  = (const float*)d_in[3];
    const float* bsrc  = (const float*)d_in[4];
    const float* Wdst  = (const float*)d_in[5];
    const float* bdst  = (const float*)d_in[6];
    const float* We    = (const float*)d_in[7];
    const float* be    = (const float*)d_in[8];
    const float* att_s = (const float*)d_in[9];
    const float* att_d = (const float*)d_in[10];
    const float* att_e = (const float*)d_in[11];
    float* out = (float*)d_out;

    // workspace layout — rec first for 16B alignment; ~41.6 MB total
    int4*  rec       = (int4*)d_ws;                            // E*16B = 25.6 MB
    unsigned short* spbf = (unsigned short*)(rec + N_EDGES);   // N*64*2B = 12.8 MB
    float* alpha_sn  = (float*)(spbf + (size_t)N_NODES * 64);  // N*4 (16B-aligned)
    float* alpha_dn  = alpha_sn + (size_t)N_NODES * 4;         // N*4
    int*   cnt       = (int*)(alpha_dn + (size_t)N_NODES * 4); // N
    int*   row_start = cnt + N_NODES;                          // N+1 (pad 4)
    int*   cursor    = row_start + N_NODES + 4;                // N
    int*   partial   = cursor + N_NODES;                       // 128
    int*   bin_cursor = partial + 128;                         // 196
    float* V         = (float*)(bin_cursor + 196 + 4);         // 584

    hipMemsetAsync(cnt, 0, (size_t)N_NODES * sizeof(int), stream);

    k_prep<<<1, 640, 0, stream>>>(We, be, att_e, Wdst, bdst, att_d, V);
    k_node_proj<<<N_NODES / 32, 256, 0, stream>>>(x, Wsrc, bsrc, att_s, V,
                                                  spbf, alpha_sn, alpha_dn);
    k_hist<<<N_EDGES / 256, 256, 0, stream>>>(ei, cnt);
    k_scan_part<<<SCAN_NBLK, 256, 0, stream>>>(cnt, partial);
    k_scan_top<<<1, 128, 0, stream>>>(partial);
    k_scan_down<<<SCAN_NBLK, 256, 0, stream>>>(cnt, partial, row_start, cursor,
                                               bin_cursor);
    k_fill_p1<<<NBLK_P1, 256, 0, stream>>>(ei, ea, V, alpha_sn, alpha_dn,
                                           bin_cursor, rec);
    k_fill_p2<<<NBIN, 256, 0, stream>>>(row_start, cursor, rec);
    k_gather<<<(N_NODES + 3) / 4, 256, 0, stream>>>(row_start, rec, spbf, out);
}

// Round 18
// 477.304 us; speedup vs baseline: 1.0794x; 1.0794x over previous
//
#include <hip/hip_runtime.h>

// EdgeGATConv on MI355X — R9 (4th resubmit; GPU-acquisition timeouts): revert
// two-phase fill (R8 regressed: p1+p2 ~136us vs 107.8 single-pass) + unroll-8
// gather for memory-level parallelism.
// R13 counters: k_gather 93us latency-bound (BW 17%, VALUBusy 41%, 4-deep MLP
// on the rec->spbf dependent chain). Deepen to 8 outstanding gathers/wave.
// Pipeline:
//   k_prep      : V[k,h] (edge readout), uD[128][4], bD[4]
//   k_node_proj : x tile in LDS; S = x@Wsrc+b -> spbf(bf16); alpha dots
//   k_hist/scan : cnt[dst]++ -> row_start, cursor
//   k_fill      : per edge: w = exp(leaky(...)); rec[slot] = {src, bf16 w x4}
//   k_gather    : wave per node, unroll-8: acc += w[h]*v; out = acc/denom

#define N_NODES 100000
#define N_EDGES 1600000
#define SCAN_B 1024
#define SCAN_NBLK ((N_NODES + SCAN_B - 1) / SCAN_B)   // 98

typedef float f32x4 __attribute__((ext_vector_type(4)));
typedef int   i32x4 __attribute__((ext_vector_type(4)));

// float -> bf16 bits, round-to-nearest-even (no NaN inputs here)
static __device__ __forceinline__ unsigned int f2bf(float f) {
    unsigned int u = __float_as_uint(f);
    return (u + 0x7fffu + ((u >> 16) & 1u)) >> 16;
}
static __device__ __forceinline__ float bf2f(unsigned int bits16) {
    return __uint_as_float(bits16 << 16);
}

// V buffer layout (floats): [0..63] V_edge[k*4+h], [64..67] b_edge dot,
// [68..579] uD[k*4+h] (k<128), [580..583] bD[h]
__global__ __launch_bounds__(640) void k_prep(
    const float* __restrict__ We, const float* __restrict__ be,
    const float* __restrict__ att_e, const float* __restrict__ Wdst,
    const float* __restrict__ bdst, const float* __restrict__ att_d,
    float* __restrict__ V)
{
    const int t = threadIdx.x;
    if (t < 64) {
        const int k = t >> 2, h = t & 3;
        float acc = 0.f;
        for (int c = 0; c < 16; ++c)
            acc += We[k * 64 + h * 16 + c] * att_e[h * 16 + c];
        V[k * 4 + h] = acc;
        if (t < 4) {
            float b = 0.f;
            for (int c = 0; c < 16; ++c)
                b += be[t * 16 + c] * att_e[t * 16 + c];
            V[64 + t] = b;
        }
    } else if (t < 576) {
        const int j = t - 64;            // 0..511
        const int k = j >> 2, h = j & 3;
        float acc = 0.f;
        for (int c = 0; c < 16; ++c)
            acc += Wdst[k * 64 + h * 16 + c] * att_d[h * 16 + c];
        V[68 + j] = acc;
    } else if (t < 580) {
        const int h = t - 576;
        float b = 0.f;
        for (int c = 0; c < 16; ++c)
            b += bdst[h * 16 + c] * att_d[h * 16 + c];
        V[580 + h] = b;
    }
}

__global__ __launch_bounds__(256) void k_node_proj(
    const float* __restrict__ x, const float* __restrict__ Wsrc,
    const float* __restrict__ bsrc, const float* __restrict__ att_src,
    const float* __restrict__ Vbuf, unsigned short* __restrict__ spbf,
    float* __restrict__ alpha_sn, float* __restrict__ alpha_dn)
{
    __shared__ float xs[32 * 132];      // 16.9 KB, stride 132 breaks bank aliasing
    __shared__ float uDs[4 * 132];      // transposed+padded: uDs[h*132 + k]
    __shared__ float bDs[4];
    const int tid = threadIdx.x;
    const int nbase = blockIdx.x * 32;

    // stage x tile: 32 rows x 128 floats = 1024 float4 (coalesced)
    {
        const f32x4* xsrc = (const f32x4*)(x + (size_t)nbase * 128);
#pragma unroll
        for (int i = 0; i < 4; ++i) {
            const int idx = tid + i * 256;      // 0..1023
            const int n = idx >> 5, q = idx & 31;
            *(f32x4*)&xs[n * 132 + q * 4] = xsrc[idx];
        }
#pragma unroll
        for (int i = 0; i < 2; ++i) {
            const int j = tid + i * 256;        // 0..511 : uD[k*4+h]
            const int k = j >> 2, h = j & 3;
            uDs[h * 132 + k] = Vbuf[68 + j];
        }
        if (tid < 4) bDs[tid] = Vbuf[580 + tid];
    }
    __syncthreads();

    const int col = tid & 63;
    const int g = tid >> 6;                     // wave id 0..3, nodes g*8..g*8+7

    float accS[8];
#pragma unroll
    for (int i = 0; i < 8; ++i) accS[i] = 0.f;

    for (int k4 = 0; k4 < 128; k4 += 4) {
        f32x4 xv[8];
#pragma unroll
        for (int i = 0; i < 8; ++i)
            xv[i] = *(const f32x4*)&xs[(g * 8 + i) * 132 + k4];  // broadcast: free
#pragma unroll
        for (int kk = 0; kk < 4; ++kk) {
            const float wsv = Wsrc[(k4 + kk) * 64 + col];        // L1-resident
#pragma unroll
            for (int i = 0; i < 8; ++i)
                accS[i] = fmaf(xv[i][kk], wsv, accS[i]);
        }
    }

    // alpha_dn GEMV: lane owns (node li, head lh), half the k-range; pair-reduce.
    const int li = col & 7, lh = (col >> 3) & 3, khalf = (col >> 5) * 64;
    float ad = 0.f;
#pragma unroll
    for (int kq = 0; kq < 16; ++kq) {
        const f32x4 xq = *(const f32x4*)&xs[(g * 8 + li) * 132 + khalf + kq * 4];
        const f32x4 uq = *(const f32x4*)&uDs[lh * 132 + khalf + kq * 4];
#pragma unroll
        for (int j = 0; j < 4; ++j)
            ad = fmaf(xq[j], uq[j], ad);
    }
    ad += __shfl_xor(ad, 32);

    const float bs = bsrc[col];
    const float as_ = att_src[col];
    const int h = col >> 4;
#pragma unroll
    for (int i = 0; i < 8; ++i) {
        const int n = nbase + g * 8 + i;
        const float vS = accS[i] + bs;
        spbf[(size_t)n * 64 + col] = (unsigned short)f2bf(vS);
        float t1 = vS * as_;
#pragma unroll
        for (int off = 8; off >= 1; off >>= 1)
            t1 += __shfl_xor(t1, off, 16);
        if ((col & 15) == 0)
            alpha_sn[n * 4 + h] = t1;
    }
    if (col < 32)
        alpha_dn[(nbase + g * 8 + li) * 4 + lh] = ad + bDs[lh];
}

__global__ __launch_bounds__(256) void k_hist(const int* __restrict__ ei,
                                               int* __restrict__ cnt)
{
    const int e = blockIdx.x * 256 + threadIdx.x;
    if (e >= N_EDGES) return;
    atomicAdd(&cnt[ei[N_EDGES + e]], 1);
}

__global__ __launch_bounds__(256) void k_scan_part(const int* __restrict__ cnt,
                                                    int* __restrict__ partial)
{
    __shared__ int red[4];
    const int t = threadIdx.x;
    const int base = blockIdx.x * SCAN_B + t * 4;
    int s = 0;
#pragma unroll
    for (int i = 0; i < 4; ++i) {
        const int idx = base + i;
        if (idx < N_NODES) s += cnt[idx];
    }
#pragma unroll
    for (int off = 32; off >= 1; off >>= 1)
        s += __shfl_xor(s, off, 64);
    if ((t & 63) == 0) red[t >> 6] = s;
    __syncthreads();
    if (t == 0)
        partial[blockIdx.x] = red[0] + red[1] + red[2] + red[3];
}

__global__ __launch_bounds__(128) void k_scan_top(int* __restrict__ partial)
{
    __shared__ int sums[128];
    const int t = threadIdx.x;
    sums[t] = (t < SCAN_NBLK) ? partial[t] : 0;
    __syncthreads();
#pragma unroll
    for (int off = 1; off < 128; off <<= 1) {
        int v = (t >= off) ? sums[t - off] : 0;
        __syncthreads();
        sums[t] += v;
        __syncthreads();
    }
    if (t < SCAN_NBLK) partial[t] = (t == 0) ? 0 : sums[t - 1];
}

__global__ __launch_bounds__(256) void k_scan_down(
    const int* __restrict__ cnt, const int* __restrict__ partial,
    int* __restrict__ row_start, int* __restrict__ cursor)
{
    __shared__ int tsum[256];
    const int t = threadIdx.x;
    const int base = blockIdx.x * SCAN_B + t * 4;
    int c[4];
#pragma unroll
    for (int i = 0; i < 4; ++i) {
        const int idx = base + i;
        c[i] = (idx < N_NODES) ? cnt[idx] : 0;
    }
    const int tot = c[0] + c[1] + c[2] + c[3];
    tsum[t] = tot;
    __syncthreads();
#pragma unroll
    for (int off = 1; off < 256; off <<= 1) {
        int v = (t >= off) ? tsum[t - off] : 0;
        __syncthreads();
        tsum[t] += v;
        __syncthreads();
    }
    int run = partial[blockIdx.x] + ((t == 0) ? 0 : tsum[t - 1]);
#pragma unroll
    for (int i = 0; i < 4; ++i) {
        const int idx = base + i;
        if (idx < N_NODES) {
            row_start[idx] = run;
            cursor[idx] = run;
        }
        run += c[i];
    }
    if (blockIdx.x == 0 && t == 0)
        row_start[N_NODES] = N_EDGES;
}

__global__ __launch_bounds__(256) void k_fill(
    const int* __restrict__ ei, const float* __restrict__ ea,
    const float* __restrict__ V, const float* __restrict__ alpha_sn,
    const float* __restrict__ alpha_dn, int* __restrict__ cursor,
    int4* __restrict__ rec)
{
    __shared__ float Vs[68];
    if (threadIdx.x < 68) Vs[threadIdx.x] = V[threadIdx.x];
    __syncthreads();

    const int e = blockIdx.x * 256 + threadIdx.x;
    if (e >= N_EDGES) return;
    const int src = ei[e];
    const int dst = ei[N_EDGES + e];

    const f32x4* ea4 = (const f32x4*)(ea + (size_t)e * 16);
    float ek[16];
    {
        f32x4 c0 = __builtin_nontemporal_load(ea4 + 0);
        f32x4 c1 = __builtin_nontemporal_load(ea4 + 1);
        f32x4 c2 = __builtin_nontemporal_load(ea4 + 2);
        f32x4 c3 = __builtin_nontemporal_load(ea4 + 3);
        ek[0]=c0.x; ek[1]=c0.y; ek[2]=c0.z; ek[3]=c0.w;
        ek[4]=c1.x; ek[5]=c1.y; ek[6]=c1.z; ek[7]=c1.w;
        ek[8]=c2.x; ek[9]=c2.y; ek[10]=c2.z; ek[11]=c2.w;
        ek[12]=c3.x; ek[13]=c3.y; ek[14]=c3.z; ek[15]=c3.w;
    }
    float a[4] = {Vs[64], Vs[65], Vs[66], Vs[67]};
#pragma unroll
    for (int k = 0; k < 16; ++k) {
#pragma unroll
        for (int h = 0; h < 4; ++h)
            a[h] = fmaf(ek[k], Vs[k * 4 + h], a[h]);
    }

    const float4 asn = *(const float4*)(alpha_sn + (size_t)src * 4);
    const float4 adn = *(const float4*)(alpha_dn + (size_t)dst * 4);
    float a0 = a[0] + asn.x + adn.x;
    float a1 = a[1] + asn.y + adn.y;
    float a2 = a[2] + asn.z + adn.z;
    float a3 = a[3] + asn.w + adn.w;
    a0 = (a0 >= 0.f) ? a0 : 0.2f * a0;
    a1 = (a1 >= 0.f) ? a1 : 0.2f * a1;
    a2 = (a2 >= 0.f) ? a2 : 0.2f * a2;
    a3 = (a3 >= 0.f) ? a3 : 0.2f * a3;

    const unsigned int w01 = f2bf(__expf(a0)) | (f2bf(__expf(a1)) << 16);
    const unsigned int w23 = f2bf(__expf(a2)) | (f2bf(__expf(a3)) << 16);

    const int slot = atomicAdd(&cursor[dst], 1);
    // plain store: measured best (R9: nt store cost +30MB RMW fetch, same time)
    rec[slot] = make_int4(src, (int)w01, (int)w23, 0);
}

// one wave per node; unroll-8 over incoming edges: 8 independent rec->spbf
// gather chains in flight per wave (R13: 4-deep was latency-bound at 93us).
__global__ __launch_bounds__(256) void k_gather(
    const int* __restrict__ row_start, const int4* __restrict__ rec,
    const unsigned short* __restrict__ spbf, float* __restrict__ out)
{
    const int lane = threadIdx.x & 63;
    const int node = (blockIdx.x * 256 + threadIdx.x) >> 6;
    const int h = lane >> 4;
    const int base = row_start[node];
    const int end = row_start[node + 1];
    const i32x4* rec4 = (const i32x4*)rec;

#define WEXT(r) bf2f(((h & 1) ? ((unsigned int)((h < 2) ? r.y : r.z) >> 16) \
                              : ((unsigned int)((h < 2) ? r.y : r.z) & 0xffffu)))
    float acc = 0.f, denom = 0.f;
    int j = base;
    for (; j + 8 <= end; j += 8) {
        i32x4 r[8];
#pragma unroll
        for (int k = 0; k < 8; ++k)
            r[k] = __builtin_nontemporal_load(rec4 + j + k);
        float v[8];
#pragma unroll
        for (int k = 0; k < 8; ++k)
            v[k] = bf2f(spbf[((size_t)r[k].x << 6) + lane]);
#pragma unroll
        for (int k = 0; k < 8; ++k) {
            const float w = WEXT(r[k]);
            denom += w;
            acc = fmaf(w, v[k], acc);
        }
    }
    for (; j + 4 <= end; j += 4) {
        const i32x4 r0 = __builtin_nontemporal_load(rec4 + j);
        const i32x4 r1 = __builtin_nontemporal_load(rec4 + j + 1);
        const i32x4 r2 = __builtin_nontemporal_load(rec4 + j + 2);
        const i32x4 r3 = __builtin_nontemporal_load(rec4 + j + 3);
        const float v0 = bf2f(spbf[((size_t)r0.x << 6) + lane]);
        const float v1 = bf2f(spbf[((size_t)r1.x << 6) + lane]);
        const float v2 = bf2f(spbf[((size_t)r2.x << 6) + lane]);
        const float v3 = bf2f(spbf[((size_t)r3.x << 6) + lane]);
        const float w0 = WEXT(r0), w1 = WEXT(r1), w2 = WEXT(r2), w3 = WEXT(r3);
        denom += (w0 + w1) + (w2 + w3);
        acc = fmaf(w0, v0, acc);
        acc = fmaf(w1, v1, acc);
        acc = fmaf(w2, v2, acc);
        acc = fmaf(w3, v3, acc);
    }
    for (; j < end; ++j) {
        const i32x4 r0 = __builtin_nontemporal_load(rec4 + j);
        const float v0 = bf2f(spbf[((size_t)r0.x << 6) + lane]);
        const float w0 = WEXT(r0);
        denom += w0;
        acc = fmaf(w0, v0, acc);
    }
#undef WEXT
    __builtin_nontemporal_store(acc / (denom + 1e-16f), &out[(size_t)node * 64 + lane]);
}

extern "C" void kernel_launch(void* const* d_in, const int* in_sizes, int n_in,
                              void* d_out, int out_size, void* d_ws, size_t ws_size,
                              hipStream_t stream) {
    const float* x     = (const float*)d_in[0];
    const int*   ei    = (const int*)d_in[1];
    const float* ea    = (const float*)d_in[2];
    const float* Wsrc  = (const float*)d_in[3];
    const float* bsrc  = (const float*)d_in[4];
    const float* Wdst  = (const float*)d_in[5];
    const float* bdst  = (const float*)d_in[6];
    const float* We    = (const float*)d_in[7];
    const float* be    = (const float*)d_in[8];
    const float* att_s = (const float*)d_in[9];
    const float* att_d = (const float*)d_in[10];
    const float* att_e = (const float*)d_in[11];
    float* out = (float*)d_out;

    // workspace layout — rec first for 16B alignment; ~41.6 MB total
    int4*  rec       = (int4*)d_ws;                            // E*16B = 25.6 MB
    unsigned short* spbf = (unsigned short*)(rec + N_EDGES);   // N*64*2B = 12.8 MB
    float* alpha_sn  = (float*)(spbf + (size_t)N_NODES * 64);  // N*4 (16B-aligned)
    float* alpha_dn  = alpha_sn + (size_t)N_NODES * 4;         // N*4
    int*   cnt       = (int*)(alpha_dn + (size_t)N_NODES * 4); // N
    int*   row_start = cnt + N_NODES;                          // N+1 (pad 4)
    int*   cursor    = row_start + N_NODES + 4;                // N
    int*   partial   = cursor + N_NODES;                       // 128
    float* V         = (float*)(partial + 128);                // 584

    hipMemsetAsync(cnt, 0, (size_t)N_NODES * sizeof(int), stream);

    k_prep<<<1, 640, 0, stream>>>(We, be, att_e, Wdst, bdst, att_d, V);
    k_node_proj<<<N_NODES / 32, 256, 0, stream>>>(x, Wsrc, bsrc, att_s, V,
                                                  spbf, alpha_sn, alpha_dn);
    k_hist<<<N_EDGES / 256, 256, 0, stream>>>(ei, cnt);
    k_scan_part<<<SCAN_NBLK, 256, 0, stream>>>(cnt, partial);
    k_scan_top<<<1, 128, 0, stream>>>(partial);
    k_scan_down<<<SCAN_NBLK, 256, 0, stream>>>(cnt, partial, row_start, cursor);
    k_fill<<<N_EDGES / 256, 256, 0, stream>>>(ei, ea, V, alpha_sn, alpha_dn,
                                              cursor, rec);
    k_gather<<<(N_NODES + 3) / 4, 256, 0, stream>>>(row_start, rec, spbf, out);
}